// Round 9
// baseline (253.415 us; speedup 1.0000x reference)
//
#include <hip/hip_runtime.h>
#include <stdint.h>

typedef _Float16 half8 __attribute__((ext_vector_type(8)));
typedef float float4v __attribute__((ext_vector_type(4)));

#define H_IN 256
#define W_IN 256
#define H_OUT 254
#define W_OUT 254
#define T_COLS 68
#define A_ROWS 408   // 6 rows * 68 cols
#define A_BYTES (A_ROWS * 128)          // 52224
#define B_SLAB  8192
#define B_BYTES (3 * B_SLAB)            // ring of 3 group slabs
#define MIN_BYTES (2 * 256 * 4)
#define SMEM_BYTES (A_BYTES + B_BYTES + MIN_BYTES)   // 78848 -> 2 blocks/CU

// ---------------------------------------------------------------------------
// Pack conv_weight (OIHW fp32) into DMA-ready layout:
//   Bp3[g][co][s16][e], g=(kh*3+kw)*2+h, s16 = q ^ ((co>>2)&3), cin=h*32+q*8+e
// ---------------------------------------------------------------------------
__global__ void pack_w_kernel(const float* __restrict__ w, _Float16* __restrict__ Bp3) {
    int idx = blockIdx.x * 256 + threadIdx.x;   // 18*4096 = 73728
    if (idx >= 73728) return;
    int g   = idx >> 12;
    int rem = idx & 4095;
    int co  = rem >> 5;
    int s16 = (rem >> 3) & 3;
    int e   = rem & 7;
    int q   = s16 ^ ((co >> 2) & 3);
    int tap = g >> 1, h = g & 1;
    int cin = h * 32 + q * 8 + e;
    int kh  = tap / 3, kw = tap - kh * 3;
    Bp3[idx] = (_Float16)w[(co * 64 + cin) * 9 + kh * 3 + kw];
}

// A-tile swizzle key (floor for 16-consecutive-row reads and stride-4 writes)
__device__ __forceinline__ int akey(int row) {
    return (((row & 7) ^ ((row >> 3) & 7)) << 4);
}

// ---------------------------------------------------------------------------
// v9: 256 threads, 4 waves of 128px x 64co (acc=128; block tile 256px x 128co).
// LDS frag traffic/group/CU: 72KB (vs v8 96KB) -> MFMA:LDS ~ 1:1.2.
// Named cur/nxt fragment double-buffer: frags(g+1) ds_read BEFORE MFMA(g);
// B ring-3 + counted vmcnt(2) + raw s_barrier (no drain in loop); setprio.
// launch_bounds(256,2): 256-reg budget, 2 blocks/CU (LDS 78.8KB).
// grid (4, 64, 16).
// ---------------------------------------------------------------------------
__global__ __launch_bounds__(256, 2)
void conv_v9_kernel(const float* __restrict__ x,
                    const _Float16* __restrict__ Bp3,
                    const float* __restrict__ bias,
                    float* __restrict__ out) {
    extern __shared__ __align__(16) char smem[];
    char*  Alds   = smem;                               // [408 rows][128 B]
    char*  Blds   = smem + A_BYTES;                     // [3][8192 B]
    float* minbuf = (float*)(smem + A_BYTES + B_BYTES); // [2][256]

    const int tid  = threadIdx.x;
    const int lane = tid & 63;
    const int wave = tid >> 6;      // 0..3
    const int ow0  = blockIdx.x * 64;
    const int oh0  = blockIdx.y * 4;
    const int nb   = blockIdx.z;
    const int wr   = wave >> 1;     // px half: 0 -> px 0..127, 1 -> 128..255
    const int wc   = wave & 1;      // co half
    const int q    = lane >> 4;
    const int lr   = lane & 15;

    // ---- issue B slab 0,1,2 DMAs (2 instr each per thread: 256thr x 16B = 4KB)
#pragma unroll
    for (int s = 0; s < 3; ++s) {
#pragma unroll
        for (int i = 0; i < 2; ++i) {
            const char* src = (const char*)Bp3 + s * B_SLAB + i * 4096 + tid * 16;
            char* dstb = Blds + s * B_SLAB + i * 4096 + (tid & ~63) * 16;
            __builtin_amdgcn_global_load_lds(
                (const __attribute__((address_space(1))) uint32_t*)src,
                (__attribute__((address_space(3))) uint32_t*)dstb, 16, 0, 0);
        }
    }

    float bv[4];
#pragma unroll
    for (int n = 0; n < 4; ++n) bv[n] = bias[wc * 64 + n * 16 + lr];

    // ---- stage A tile: 816 items (8cin x 4px each), reg-transpose, swizzled
    {
        const float* xb = x + (size_t)nb * (64 * H_IN * W_IN);
        for (int id = tid; id < 816; id += 256) {
            int oct  = (unsigned)id / 102u;
            int pxq  = id - oct * 102;
            int row0 = pxq * 4;
            int r    = (unsigned)row0 / (unsigned)T_COLS;
            int c    = row0 - r * T_COLS;
            int ih   = oh0 + r; if (ih > H_IN - 1) ih = H_IN - 1;
            int iw   = ow0 + c; if (iw > W_IN - 4) iw = W_IN - 4;
            const float* src = xb + (size_t)(oct * 8) * (H_IN * W_IN)
                                  + (size_t)ih * W_IN + iw;
            float4v f[8];
#pragma unroll
            for (int u = 0; u < 8; ++u)
                f[u] = *(const float4v*)(src + (size_t)u * (H_IN * W_IN));
#pragma unroll
            for (int j = 0; j < 4; ++j) {
                int row = row0 + j;
                half8 hv;
#pragma unroll
                for (int u = 0; u < 8; ++u) hv[u] = (_Float16)f[u][j];
                *(half8*)(Alds + row * 128 + ((oct * 16) ^ akey(row))) = hv;
            }
        }
    }
    __syncthreads();   // drains vmcnt(0): A visible AND slabs 0..2 landed

    const int bslot = (q ^ ((lr >> 2) & 3)) << 4;
    const int bco   = (wc * 64 + lr) * 64;

    float4v acc[8][4];
#pragma unroll
    for (int m = 0; m < 8; ++m)
#pragma unroll
        for (int n = 0; n < 4; ++n)
#pragma unroll
            for (int i = 0; i < 4; ++i) acc[m][n][i] = 0.0f;

    half8 acur[8], bcur[4], anxt[8], bnxt[4];

    // frag loaders (gg is always an unroll-time constant at call sites)
    auto loadA = [&](int gg, half8 (&dst)[8]) {
        const int tap = gg >> 1, hh = gg & 1;
        const int kh = tap / 3, kw = tap - kh * 3;
        const int kb = hh * 64 + q * 16;
#pragma unroll
        for (int m = 0; m < 8; ++m) {
            int row = (wr * 2 + (m >> 2) + kh) * T_COLS + (m & 3) * 16 + lr + kw;
            dst[m] = *(const half8*)(Alds + row * 128 + (kb ^ akey(row)));
        }
    };
    auto loadB = [&](int gg, half8 (&dst)[4]) {
#pragma unroll
        for (int n = 0; n < 4; ++n)
            dst[n] = *(const half8*)(Blds + (gg % 3) * B_SLAB + bco + n * 1024 + bslot);
    };

    loadA(0, acur);
    loadB(0, bcur);

#pragma unroll
    for (int g = 0; g < 18; ++g) {
        // ---- counted wait: slab g+1 landed (ring math: 2 DMA instr/slab,
        // issued through slab g+2 => leave 2 outstanding). No drain.
        if (g < 16)      asm volatile("s_waitcnt vmcnt(2)" ::: "memory");
        else if (g == 16) asm volatile("s_waitcnt vmcnt(0)" ::: "memory");
        if (g < 17) __builtin_amdgcn_s_barrier();

        // ---- issue DMA for slab g+3 into slot g%3 (slab g's frags were
        // consumed from LDS during iter g-1; all waves past barrier g)
        if (g < 15) {
#pragma unroll
            for (int i = 0; i < 2; ++i) {
                const char* src = (const char*)Bp3 + (size_t)(g + 3) * B_SLAB
                                  + i * 4096 + tid * 16;
                char* dstb = Blds + ((g + 3) % 3) * B_SLAB + i * 4096
                                  + (tid & ~63) * 16;
                __builtin_amdgcn_global_load_lds(
                    (const __attribute__((address_space(1))) uint32_t*)src,
                    (__attribute__((address_space(3))) uint32_t*)dstb, 16, 0, 0);
            }
        }

        // ---- prefetch frags(g+1) into the other register set
        if (g < 17) {
            if (g & 1) { loadA(g + 1, acur); loadB(g + 1, bcur); }
            else       { loadA(g + 1, anxt); loadB(g + 1, bnxt); }
            // pin emission: the 12 prefetch DS reads come before the MFMAs
            __builtin_amdgcn_sched_group_barrier(0x100, 12, 0);
        }

        // ---- MFMA cluster on current frags (reads issued one full group ago)
        half8 (&A)[8] = (g & 1) ? anxt : acur;
        half8 (&B)[4] = (g & 1) ? bnxt : bcur;
        __builtin_amdgcn_s_setprio(1);
#pragma unroll
        for (int m = 0; m < 8; ++m)
#pragma unroll
            for (int n = 0; n < 4; ++n)
                acc[m][n] = __builtin_amdgcn_mfma_f32_16x16x32_f16(
                    A[m], B[n], acc[m][n], 0, 0, 0);
        __builtin_amdgcn_s_setprio(0);
    }

    // ---- epilogue: + bias, min over co, double tanh
#pragma unroll
    for (int m = 0; m < 8; ++m) {
        float4v v;
#pragma unroll
        for (int n = 0; n < 4; ++n) {
#pragma unroll
            for (int i = 0; i < 4; ++i) {
                float t = acc[m][n][i] + bv[n];
                v[i] = (n == 0) ? t : fminf(v[i], t);
            }
        }
#pragma unroll
        for (int off = 1; off < 16; off <<= 1)
#pragma unroll
            for (int i = 0; i < 4; ++i)
                v[i] = fminf(v[i], __shfl_xor(v[i], off, 64));
        if (lr == 0) {
#pragma unroll
            for (int i = 0; i < 4; ++i)
                minbuf[wc * 256 + wr * 128 + m * 16 + q * 4 + i] = v[i];
        }
    }
    __syncthreads();

    {
        int r = tid >> 6, c = tid & 63;
        int oh = oh0 + r, ow = ow0 + c;
        if (oh < H_OUT && ow < W_OUT) {
            float mv = fminf(minbuf[tid], minbuf[256 + tid]);
            out[((size_t)nb * H_OUT + oh) * W_OUT + ow] = tanhf(tanhf(mv));
        }
    }
}

extern "C" void kernel_launch(void* const* d_in, const int* in_sizes, int n_in,
                              void* d_out, int out_size, void* d_ws, size_t ws_size,
                              hipStream_t stream) {
    const float* x    = (const float*)d_in[0];
    const float* w    = (const float*)d_in[1];
    const float* bias = (const float*)d_in[2];
    float* out        = (float*)d_out;
    _Float16* Bp3     = (_Float16*)d_ws;   // 147456 B

    pack_w_kernel<<<dim3(288), dim3(256), 0, stream>>>(w, Bp3);
    conv_v9_kernel<<<dim3(4, 64, 16), dim3(256), SMEM_BYTES, stream>>>(x, Bp3, bias, out);
}

// Round 10
// 226.452 us; speedup vs baseline: 1.1191x; 1.1191x over previous
//
#include <hip/hip_runtime.h>
#include <stdint.h>

typedef _Float16 half8 __attribute__((ext_vector_type(8)));
typedef float float4v __attribute__((ext_vector_type(4)));

#define H_IN 256
#define W_IN 256
#define H_OUT 254
#define W_OUT 254
#define T_COLS 68
#define A_ROWS 408   // 6 rows * 68 cols
#define A_BYTES (A_ROWS * 128)          // 52224
#define B_SLAB  8192
#define B_BYTES (4 * B_SLAB)            // ring of 4 group slabs (race margin = 2 groups)
#define MIN_BYTES (2 * 256 * 4)
#define SMEM_BYTES (A_BYTES + B_BYTES + MIN_BYTES)   // 87040 -> 1 block/CU

// ---------------------------------------------------------------------------
// Pack conv_weight (OIHW fp32) into DMA-ready layout:
//   Bp3[g][co][s16][e], g=(kh*3+kw)*2+h, s16 = q ^ ((co>>2)&3), cin=h*32+q*8+e
// ---------------------------------------------------------------------------
__global__ void pack_w_kernel(const float* __restrict__ w, _Float16* __restrict__ Bp3) {
    int idx = blockIdx.x * 256 + threadIdx.x;   // 18*4096 = 73728
    if (idx >= 73728) return;
    int g   = idx >> 12;
    int rem = idx & 4095;
    int co  = rem >> 5;
    int s16 = (rem >> 3) & 3;
    int e   = rem & 7;
    int q   = s16 ^ ((co >> 2) & 3);
    int tap = g >> 1, h = g & 1;
    int cin = h * 32 + q * 8 + e;
    int kh  = tap / 3, kw = tap - kh * 3;
    Bp3[idx] = (_Float16)w[(co * 64 + cin) * 9 + kh * 3 + kw];
}

// A-tile swizzle key (bank-floor for 16-consecutive-row reads and stride-4 writes)
__device__ __forceinline__ int akey(int row) {
    return (((row & 7) ^ ((row >> 3) & 7)) << 4);
}

// ---------------------------------------------------------------------------
// v10: v8 geometry (512 thr, 8 waves x 64px x 64co; A staged once; B DMA ring)
// + v9's PINNED depth-1 fragment prefetch, with register budget that fits:
//   acc 64 + frag double-buffer 64 + addr ~30 < 256 (launch_bounds(512,2)).
// Ring-4 B slabs: slot for slab s overwritten 2 groups after its last read
// (queued-ds_read vs DMA-land race margin). Counted vmcnt(1) (never 0 until
// g=16), barrier only while DMAs issue, SGB{DS_READ 8, MFMA 16}, setprio.
// 1 block/CU (LDS 87KB), 2 waves/SIMD: ILP carries latency.
// grid (4, 64, 16).
// ---------------------------------------------------------------------------
__global__ __launch_bounds__(512, 2)
void conv_v10_kernel(const float* __restrict__ x,
                     const _Float16* __restrict__ Bp3,
                     const float* __restrict__ bias,
                     float* __restrict__ out) {
    extern __shared__ __align__(16) char smem[];
    char*  Alds   = smem;                               // [408 rows][128 B]
    char*  Blds   = smem + A_BYTES;                     // [4][8192 B]
    float* minbuf = (float*)(smem + A_BYTES + B_BYTES); // [2][256]

    const int tid  = threadIdx.x;
    const int lane = tid & 63;
    const int wave = tid >> 6;      // 0..7
    const int ow0  = blockIdx.x * 64;
    const int oh0  = blockIdx.y * 4;
    const int nb   = blockIdx.z;
    const int wr   = wave >> 1;     // output row within tile (0..3)
    const int wc   = wave & 1;      // co half
    const int q    = lane >> 4;
    const int lr   = lane & 15;

    // ---- issue B slab 0,1,2 DMAs (512 thr x 16 B = one 8KB slab per instr)
#pragma unroll
    for (int s = 0; s < 3; ++s) {
        const char* src = (const char*)Bp3 + s * B_SLAB + tid * 16;
        char* dstb = Blds + s * B_SLAB + (tid & ~63) * 16;
        __builtin_amdgcn_global_load_lds(
            (const __attribute__((address_space(1))) uint32_t*)src,
            (__attribute__((address_space(3))) uint32_t*)dstb, 16, 0, 0);
    }

    float bv[4];
#pragma unroll
    for (int n = 0; n < 4; ++n) bv[n] = bias[wc * 64 + n * 16 + lr];

    // ---- stage A tile: 816 items (8cin x 4px each), reg-transpose, swizzled
    {
        const float* xb = x + (size_t)nb * (64 * H_IN * W_IN);
#pragma unroll
        for (int k = 0; k < 2; ++k) {
            int id = tid + 512 * k;
            if (id < 816) {
                int oct  = (unsigned)id / 102u;
                int pxq  = id - oct * 102;
                int row0 = pxq * 4;
                int r    = (unsigned)row0 / (unsigned)T_COLS;
                int c    = row0 - r * T_COLS;
                int ih   = oh0 + r; if (ih > H_IN - 1) ih = H_IN - 1;
                int iw   = ow0 + c; if (iw > W_IN - 4) iw = W_IN - 4;
                const float* src = xb + (size_t)(oct * 8) * (H_IN * W_IN)
                                      + (size_t)ih * W_IN + iw;
                float4v f[8];
#pragma unroll
                for (int u = 0; u < 8; ++u)
                    f[u] = *(const float4v*)(src + (size_t)u * (H_IN * W_IN));
#pragma unroll
                for (int j = 0; j < 4; ++j) {
                    int row = row0 + j;
                    half8 hv;
#pragma unroll
                    for (int u = 0; u < 8; ++u) hv[u] = (_Float16)f[u][j];
                    *(half8*)(Alds + row * 128 + ((oct * 16) ^ akey(row))) = hv;
                }
            }
        }
    }
    __syncthreads();   // drains vmcnt: A visible AND slabs 0..2 landed

    const int bslot = (q ^ ((lr >> 2) & 3)) << 4;
    const int bco   = (wc * 64 + lr) * 64;

    float4v acc[4][4];
#pragma unroll
    for (int m = 0; m < 4; ++m)
#pragma unroll
        for (int n = 0; n < 4; ++n)
#pragma unroll
            for (int i = 0; i < 4; ++i) acc[m][n][i] = 0.0f;

    half8 acur[4], bcur[4], anxt[4], bnxt[4];

    auto loadA = [&](int gg, half8 (&dst)[4]) {   // gg unroll-constant
        const int tap = gg >> 1, hh = gg & 1;
        const int kh = tap / 3, kw = tap - kh * 3;
        const int kb = hh * 64 + q * 16;
#pragma unroll
        for (int m = 0; m < 4; ++m) {
            int row = (wr + kh) * T_COLS + m * 16 + lr + kw;
            dst[m] = *(const half8*)(Alds + row * 128 + (kb ^ akey(row)));
        }
    };
    auto loadB = [&](int gg, half8 (&dst)[4]) {
#pragma unroll
        for (int n = 0; n < 4; ++n)
            dst[n] = *(const half8*)(Blds + (gg & 3) * B_SLAB + bco + n * 1024 + bslot);
    };

    loadA(0, acur);   // slab 0 resident (post-sync)
    loadB(0, bcur);

#pragma unroll
    for (int g = 0; g < 18; ++g) {
        // counted wait: slabs <= g+1 landed (1 DMA instr per slab, in-order)
        if (g < 16)       asm volatile("s_waitcnt vmcnt(1)" ::: "memory");
        else if (g == 16) asm volatile("s_waitcnt vmcnt(0)" ::: "memory");
        if (g < 16) __builtin_amdgcn_s_barrier();

        // issue DMA slab g+3 into slot (g+3)&3: that slot held slab g-1,
        // last read in iter g-2, two barriers ago -> queued-read race margin
        if (g < 15) {
            const char* src = (const char*)Bp3 + (size_t)(g + 3) * B_SLAB + tid * 16;
            char* dstb = Blds + ((g + 3) & 3) * B_SLAB + (tid & ~63) * 16;
            __builtin_amdgcn_global_load_lds(
                (const __attribute__((address_space(1))) uint32_t*)src,
                (__attribute__((address_space(3))) uint32_t*)dstb, 16, 0, 0);
        }

        // prefetch frags(g+1) into the other named set (pinned below)
        if (g < 17) {
            if (g & 1) { loadA(g + 1, acur); loadB(g + 1, bcur); }
            else       { loadA(g + 1, anxt); loadB(g + 1, bnxt); }
        }

        half8 (&A)[4] = (g & 1) ? anxt : acur;
        half8 (&B)[4] = (g & 1) ? bnxt : bcur;

        // pin schedule: 8 prefetch DS reads, then the 16 MFMAs
        __builtin_amdgcn_sched_group_barrier(0x100, 8, 0);
        __builtin_amdgcn_s_setprio(1);
#pragma unroll
        for (int m = 0; m < 4; ++m)
#pragma unroll
            for (int n = 0; n < 4; ++n)
                acc[m][n] = __builtin_amdgcn_mfma_f32_16x16x32_f16(
                    A[m], B[n], acc[m][n], 0, 0, 0);
        __builtin_amdgcn_s_setprio(0);
        __builtin_amdgcn_sched_group_barrier(0x8, 16, 0);
    }

    // ---- epilogue: + bias, min over co, double tanh
#pragma unroll
    for (int m = 0; m < 4; ++m) {
        float4v v;
#pragma unroll
        for (int n = 0; n < 4; ++n) {
#pragma unroll
            for (int i = 0; i < 4; ++i) {
                float t = acc[m][n][i] + bv[n];
                v[i] = (n == 0) ? t : fminf(v[i], t);
            }
        }
#pragma unroll
        for (int off = 1; off < 16; off <<= 1)
#pragma unroll
            for (int i = 0; i < 4; ++i)
                v[i] = fminf(v[i], __shfl_xor(v[i], off, 64));
        if (lr == 0) {
#pragma unroll
            for (int i = 0; i < 4; ++i)
                minbuf[wc * 256 + wr * 64 + m * 16 + q * 4 + i] = v[i];
        }
    }
    __syncthreads();

    if (tid < 256) {
        int r = tid >> 6, c = tid & 63;
        int oh = oh0 + r, ow = ow0 + c;
        if (oh < H_OUT && ow < W_OUT) {
            float mv = fminf(minbuf[tid], minbuf[256 + tid]);
            out[((size_t)nb * H_OUT + oh) * W_OUT + ow] = tanhf(tanhf(mv));
        }
    }
}

extern "C" void kernel_launch(void* const* d_in, const int* in_sizes, int n_in,
                              void* d_out, int out_size, void* d_ws, size_t ws_size,
                              hipStream_t stream) {
    const float* x    = (const float*)d_in[0];
    const float* w    = (const float*)d_in[1];
    const float* bias = (const float*)d_in[2];
    float* out        = (float*)d_out;
    _Float16* Bp3     = (_Float16*)d_ws;   // 147456 B

    pack_w_kernel<<<dim3(288), dim3(256), 0, stream>>>(w, Bp3);
    conv_v10_kernel<<<dim3(4, 64, 16), dim3(512), SMEM_BYTES, stream>>>(x, Bp3, bias, out);
}